// Round 14
// baseline (373.165 us; speedup 1.0000x reference)
//
#include <hip/hip_runtime.h>
#include <cstdint>
#include <cstddef>

typedef __attribute__((ext_vector_type(4))) float f4;
typedef __attribute__((ext_vector_type(8))) short bf16x8;
typedef __attribute__((ext_vector_type(8))) unsigned short u16x8;
typedef unsigned long long u64;

// ---------------- helpers ----------------
__device__ __forceinline__ unsigned short f2bf(float x) {
    unsigned u = __float_as_uint(x);
    u += 0x7fffu + ((u >> 16) & 1u);
    return (unsigned short)(u >> 16);
}
__device__ __forceinline__ float bf2f(unsigned short h) {
    return __uint_as_float(((unsigned)h) << 16);
}
__device__ __forceinline__ unsigned cvtpk_bf16(float lo, float hi) {
    unsigned r;
    asm("v_cvt_pk_bf16_f32 %0, %1, %2" : "=v"(r) : "v"(lo), "v"(hi));
    return r;
}
__device__ __forceinline__ float fast_exp2(float x) { return __builtin_amdgcn_exp2f(x); }
__device__ __forceinline__ float fast_log2(float x) { return __builtin_amdgcn_logf(x); }
__device__ __forceinline__ void gll16(const void* g, void* l) {
    __builtin_amdgcn_global_load_lds(
        (const __attribute__((address_space(1))) unsigned int*)g,
        (__attribute__((address_space(3))) unsigned int*)l, 16, 0, 0);
}
__device__ __forceinline__ f4 mfma16(bf16x8 a, bf16x8 b, f4 c) {
    return __builtin_amdgcn_mfma_f32_16x16x32_bf16(a, b, c, 0, 0, 0);
}

// ---------------- weight prep: W[K][N] fp32 -> W^T[N][K] bf16 (hi only) ----------------
__global__ __launch_bounds__(256)
void prep_w_kernel(const float* __restrict__ Wq, const float* __restrict__ Wk,
                   const float* __restrict__ Wv, const float* __restrict__ Wo,
                   unsigned short* __restrict__ wt)   // 4 x 1048576
{
    const int w = blockIdx.z;
    const float* W = w == 0 ? Wq : (w == 1 ? Wk : (w == 2 ? Wv : Wo));
    unsigned short* hi = wt + (size_t)w * 1048576;

    const int kb = blockIdx.x << 6, nb = blockIdx.y << 6;
    __shared__ float T[64][68];
    const int tid = threadIdx.x;
    {
        const int r = tid >> 2, c0 = (tid & 3) << 4;
        const float* src = W + (size_t)(kb + r) * 1024 + nb + c0;
        *(f4*)&T[r][c0 + 0]  = *(const f4*)(src + 0);
        *(f4*)&T[r][c0 + 4]  = *(const f4*)(src + 4);
        *(f4*)&T[r][c0 + 8]  = *(const f4*)(src + 8);
        *(f4*)&T[r][c0 + 12] = *(const f4*)(src + 12);
    }
    __syncthreads();
    {
        const int n = tid & 63, ks = (tid >> 6) << 4;
        unsigned short vh[16];
        #pragma unroll
        for (int j = 0; j < 16; ++j) vh[j] = f2bf(T[ks + j][n]);
        const size_t dst = (size_t)(nb + n) * 1024 + kb + ks;
        *(u16x8*)(hi + dst)     = *(u16x8*)&vh[0];
        *(u16x8*)(hi + dst + 8) = *(u16x8*)&vh[8];
    }
}

// ---------------- activation prep: q/k/v fp32 -> bf16 ----------------
__global__ __launch_bounds__(256)
void prep_a_kernel(const float* __restrict__ q, const float* __restrict__ k,
                   const float* __restrict__ v, unsigned short* __restrict__ a_hi)
{
    const int gid = blockIdx.x * 256 + threadIdx.x;
    const int z = gid >> 18;
    const int rem = gid & 262143;
    const float* src = z == 0 ? q : (z == 1 ? k : v);
    const size_t off = (size_t)rem << 4;
    const float* s = src + off;
    unsigned short* hi = a_hi + ((size_t)z << 22) + off;
    float xs[16];
    *(f4*)&xs[0]  = *(const f4*)(s + 0);
    *(f4*)&xs[4]  = *(const f4*)(s + 4);
    *(f4*)&xs[8]  = *(const f4*)(s + 8);
    *(f4*)&xs[12] = *(const f4*)(s + 12);
    unsigned short hv[16];
    #pragma unroll
    for (int j = 0; j < 16; ++j) hv[j] = f2bf(xs[j]);
    *(u16x8*)(hi + 0) = *(u16x8*)&hv[0];
    *(u16x8*)(hi + 8) = *(u16x8*)&hv[8];
}

// ---------------- V transpose: v_hi [b,h,s,d] -> vT [b,h,d,s] ----------------
__global__ __launch_bounds__(256)
void vtr_kernel(const unsigned short* __restrict__ v_hi, unsigned short* __restrict__ vT)
{
    __shared__ unsigned short T[64][80];
    const int bh = blockIdx.y;
    const int s0 = blockIdx.x << 6;
    const int tid = threadIdx.x;
    const size_t base = (size_t)bh * 131072;
    {
        const int s = tid >> 2, dq = (tid & 3) << 4;
        const unsigned short* src = v_hi + base + (size_t)(s0 + s) * 64 + dq;
        u16x8 a = *(const u16x8*)src;
        u16x8 b = *(const u16x8*)(src + 8);
        *(u16x8*)&T[s][dq]     = a;
        *(u16x8*)&T[s][dq + 8] = b;
    }
    __syncthreads();
    {
        const int d = tid >> 2, sq = (tid & 3) << 4;
        unsigned short o[16];
        #pragma unroll
        for (int j = 0; j < 16; ++j) o[j] = T[sq + j][d];
        unsigned short* dst = vT + base + ((size_t)d << 11) + s0 + sq;
        *(u16x8*)dst       = *(u16x8*)&o[0];
        *(u16x8*)(dst + 8) = *(u16x8*)&o[8];
    }
}

// ---------------- 1-term 128x128 GEMM core (plain bf16), BK=64, 32 KB LDS ----------------
__device__ __forceinline__ void gemm1_core(
    const unsigned short* __restrict__ AH, const unsigned short* __restrict__ WH,
    const float* __restrict__ bias, int bm, int bn, int mode,
    unsigned short* __restrict__ o_hi, float* __restrict__ o_f32, unsigned char* lds)
{
    unsigned char* As = lds;            // [128 rows][128B k], swz (r&7)
    unsigned char* Bs = lds + 16384;

    const int tid = threadIdx.x, lane = tid & 63, wave = tid >> 6;
    const int wm = wave >> 1, wn = wave & 1;
    const int cx = lane & 15, lg = lane >> 4;
    const int l3 = lane >> 3, p3 = lane & 7;
    const int m0 = bm << 7, n0 = bn << 7;

    f4 acc[4][4];
    #pragma unroll
    for (int i = 0; i < 4; ++i)
        #pragma unroll
        for (int j = 0; j < 4; ++j) acc[i][j] = (f4){0.f, 0.f, 0.f, 0.f};

    #pragma unroll 1
    for (int k0 = 0; k0 < 1024; k0 += 64) {
        __syncthreads();
        #pragma unroll
        for (int c = 0; c < 4; ++c) {
            const int cb = (c << 2) + wave;
            const int row = (cb << 3) + l3;
            const int lgx = p3 ^ (row & 7);
            gll16(AH + (size_t)(m0 + row) * 1024 + k0 + (lgx << 3),
                  As + (cb << 10) + (lane << 4));
            gll16(WH + (size_t)(n0 + row) * 1024 + k0 + (lgx << 3),
                  Bs + (cb << 10) + (lane << 4));
        }
        __syncthreads();
        #pragma unroll
        for (int ks = 0; ks < 2; ++ks) {
            bf16x8 ah[4], bh[4];
            #pragma unroll
            for (int t = 0; t < 4; ++t) {
                const int r = (wm << 6) + (t << 4) + cx;
                ah[t] = *(const bf16x8*)(As + r * 128 + (((((ks << 2) + lg)) ^ (r & 7)) << 4));
                const int n = (wn << 6) + (t << 4) + cx;
                bh[t] = *(const bf16x8*)(Bs + n * 128 + (((((ks << 2) + lg)) ^ (n & 7)) << 4));
            }
            #pragma unroll
            for (int i = 0; i < 4; ++i)
                #pragma unroll
                for (int j = 0; j < 4; ++j)
                    acc[i][j] = mfma16(ah[i], bh[j], acc[i][j]);
        }
    }

    float bv4[4];
    #pragma unroll
    for (int j = 0; j < 4; ++j) bv4[j] = bias[n0 + (wn << 6) + (j << 4) + cx];

    #pragma unroll
    for (int i = 0; i < 4; ++i)
        #pragma unroll
        for (int j = 0; j < 4; ++j) {
            const int n = n0 + (wn << 6) + (j << 4) + cx;
            const int mb = m0 + (wm << 6) + (i << 4) + (lg << 2);
            if (mode == 2) {
                #pragma unroll
                for (int r = 0; r < 4; ++r)
                    o_f32[(size_t)(mb + r) * 1024 + n] = acc[i][j][r] + bv4[j];
            } else {
                const int b = mb >> 11, hh = n >> 6, d = n & 63;
                #pragma unroll
                for (int r = 0; r < 4; ++r) {
                    const int s = (mb + r) & 2047;
                    o_hi[(((size_t)(b * 16 + hh)) * 2048 + s) * 64 + d] = f2bf(acc[i][j][r] + bv4[j]);
                }
            }
        }
}

__global__ __launch_bounds__(256)
void qkv_gemm_kernel(const unsigned short* __restrict__ a_hi,
                     const unsigned short* __restrict__ wt,
                     const float* __restrict__ bq, const float* __restrict__ bk,
                     const float* __restrict__ bv,
                     unsigned short* __restrict__ q_hi, unsigned short* __restrict__ k_hi,
                     unsigned short* __restrict__ v_hi)
{
    __shared__ __align__(16) unsigned char lds[32768];
    const int f = blockIdx.x;                     // 768, %8==0 -> bijective XCD swizzle
    const int id2 = (f & 7) * 96 + (f >> 3);
    const int z = id2 >> 8;
    const int rem = id2 & 255;
    const int bn = rem >> 5, bm = rem & 31;
    const unsigned short* AH = a_hi + ((size_t)z << 22);
    const unsigned short* WH = wt + (size_t)z * 1048576;
    const float* bias = z == 0 ? bq : (z == 1 ? bk : bv);
    unsigned short* ohi = z == 0 ? q_hi : (z == 1 ? k_hi : v_hi);
    gemm1_core(AH, WH, bias, bm, bn, 1, ohi, nullptr, lds);
}

__global__ __launch_bounds__(256)
void out_gemm_kernel(const unsigned short* __restrict__ ctx_hi,
                     const unsigned short* __restrict__ wt_o,
                     const float* __restrict__ bo, float* __restrict__ out)
{
    __shared__ __align__(16) unsigned char lds[32768];
    const int f = blockIdx.x;                     // 256
    const int id2 = (f & 7) * 32 + (f >> 3);
    const int bn = id2 >> 5, bm = id2 & 31;
    gemm1_core(ctx_hi, wt_o, bo, bm, bn, 2, nullptr, out, lds);
}

// ---------------- fused attention: barrier-free reg-prefetch pass 1, LDS pass 2 ----------------
__global__ __launch_bounds__(256, 3)
void attn_kernel(const unsigned short* __restrict__ q_hi, const unsigned short* __restrict__ k_hi,
                 const unsigned short* __restrict__ vT, const float* __restrict__ mask,
                 float* __restrict__ attn, unsigned short* __restrict__ ctx_hi)
{
    __shared__ __align__(16) unsigned char lds[40960];
    unsigned char* K1 = lds;             // 2 x 8KB: K  [64 s][128B d], swz (s&7)  (pass 2)
    unsigned char* Vs = lds + 16384;     // 2 x 8KB: V^T [64 d][128B s], swz (d&7) (pass 2)
    unsigned char* Ps = lds + 32768;     //     8KB: P [64 q][128B k]              (pass 2)

    const int f = blockIdx.x;                       // 1024, %8==0 bijective
    const int swzf = (f & 7) * 128 + (f >> 3);
    const int bh = swzf >> 5;
    const int q0 = (swzf & 31) << 6;
    const int b = bh >> 4, h = bh & 15;
    const int tid = threadIdx.x, lane = tid & 63, wave = tid >> 6;
    const int cx = lane & 15, lg = lane >> 4;
    const int l3 = lane >> 3, p3 = lane & 7;
    const size_t base = (size_t)bh * 131072;        // k_hi [b,h,s,d] and vT [b,h,d,s]
    const float* mg = mask + (size_t)b * 2048;

    constexpr float C2   = 0.18033688011112042f;     // 0.125 * log2(e)
    constexpr float M2   = -1.4426950408889634e9f;   // -1e9 * log2(e)
    constexpr float MFIX = 4.0f;                     // fixed softmax shift (log2 domain)

    // ---- Q fragments: direct global (lane holds Q[q0+wave*16+cx][(ks*4+lg)*8 ..]) ----
    bf16x8 qb[2];
    #pragma unroll
    for (int ks = 0; ks < 2; ++ks)
        qb[ks] = *(const bf16x8*)(q_hi + base + (size_t)(q0 + (wave << 4) + cx) * 64
                                  + (((ks << 2) + lg) << 3));

    // ================= pass 1: barrier-free, reg double-buffered K =================
    float l4[4] = {0.f, 0.f, 0.f, 0.f};

    const unsigned short* kfrag_base = k_hi + base + (size_t)cx * 64 + (((0 << 2) + lg) << 3);
    // per-(nt,ks) fragment address for tile t: k_hi + base + (t*64 + nt*16 + cx)*64 + (ks*4+lg)*8

    bf16x8 kA[4][2], kB[4][2];
    f4 mA[4], mB[4];

    #pragma unroll
    for (int nt = 0; nt < 4; ++nt) {
        const size_t r = (size_t)((nt << 4) + cx) * 64;
        #pragma unroll
        for (int ks = 0; ks < 2; ++ks)
            kA[nt][ks] = *(const bf16x8*)(k_hi + base + r + (((ks << 2) + lg) << 3));
        mA[nt] = *(const f4*)(mg + (nt << 4) + (lg << 2));
    }

    auto p1_body = [&](bf16x8 (&kc)[4][2], bf16x8 (&kn)[4][2],
                       f4 (&mc)[4], f4 (&mn)[4], int t) {
        const int k0 = t << 6;
        if (t < 31) {
            #pragma unroll
            for (int nt = 0; nt < 4; ++nt) {
                const size_t r = (size_t)(k0 + 64 + (nt << 4) + cx) * 64;
                #pragma unroll
                for (int ks = 0; ks < 2; ++ks)
                    kn[nt][ks] = *(const bf16x8*)(k_hi + base + r + (((ks << 2) + lg) << 3));
                mn[nt] = *(const f4*)(mg + k0 + 64 + (nt << 4) + (lg << 2));
            }
        }
        f4 s[4];
        #pragma unroll
        for (int nt = 0; nt < 4; ++nt) {
            s[nt] = mfma16(kc[nt][0], qb[0], (f4){0.f, 0.f, 0.f, 0.f});
            s[nt] = mfma16(kc[nt][1], qb[1], s[nt]);
        }
        #pragma unroll
        for (int nt = 0; nt < 4; ++nt) {
            l4[nt] += fast_exp2(fmaf(s[nt][0], C2, fmaf(mc[nt][0], M2, -MFIX)))
                    + fast_exp2(fmaf(s[nt][1], C2, fmaf(mc[nt][1], M2, -MFIX)))
                    + fast_exp2(fmaf(s[nt][2], C2, fmaf(mc[nt][2], M2, -MFIX)))
                    + fast_exp2(fmaf(s[nt][3], C2, fmaf(mc[nt][3], M2, -MFIX)));
        }
    };

    #pragma unroll 1
    for (int t = 0; t < 32; t += 2) {
        p1_body(kA, kB, mA, mB, t);
        p1_body(kB, kA, mB, mA, t + 1);
    }

    float ssum = (l4[0] + l4[1]) + (l4[2] + l4[3]);
    ssum += __shfl_xor(ssum, 16);
    ssum += __shfl_xor(ssum, 32);
    const float cofs = -MFIX - fast_log2(ssum);      // P = exp2(logit2 + m*M2 + cofs)

    // ================= pass 2: LDS-staged K/V, one barrier per tile =================
    #pragma unroll
    for (int c = 0; c < 2; ++c) {
        const int cb = (c << 2) + wave;
        const int row = (cb << 3) + l3;
        const int lgx = p3 ^ (row & 7);
        gll16(k_hi + base + (size_t)row * 64 + (lgx << 3),
              K1 + (cb << 10) + (lane << 4));
        gll16(vT + base + ((size_t)row << 11) + (lgx << 3),
              Vs + (cb << 10) + (lane << 4));
    }
    f4 mrc[4];
    #pragma unroll
    for (int nt = 0; nt < 4; ++nt) mrc[nt] = *(const f4*)(mg + (nt << 4) + (lg << 2));
    asm volatile("s_waitcnt vmcnt(0)" ::: "memory");
    __builtin_amdgcn_s_barrier();

    f4 cacc[4];
    #pragma unroll
    for (int nt = 0; nt < 4; ++nt) cacc[nt] = (f4){0.f, 0.f, 0.f, 0.f};

    float* arow = attn + ((size_t)bh * 2048 + q0 + (wave << 4) + cx) * 2048;
    const unsigned psSwz = (unsigned)((cx & 7) << 4);

    #pragma unroll 1
    for (int t = 0; t < 32; ++t) {
        const int p = t & 1;
        const int k0 = t << 6;
        // [A] stage K(t+1), V(t+1); mask(t+1) -> regs   (4 gll16 + 4 loads)
        f4 mrn[4];
        if (t < 31) {
            #pragma unroll
            for (int c = 0; c < 2; ++c) {
                const int cb = (c << 2) + wave;
                const int row = (cb << 3) + l3;
                const int lgx = p3 ^ (row & 7);
                gll16(k_hi + base + (size_t)(k0 + 64 + row) * 64 + (lgx << 3),
                      K1 + ((p ^ 1) << 13) + (cb << 10) + (lane << 4));
                gll16(vT + base + ((size_t)row << 11) + k0 + 64 + (lgx << 3),
                      Vs + ((p ^ 1) << 13) + (cb << 10) + (lane << 4));
            }
            __builtin_amdgcn_sched_barrier(0);
            #pragma unroll
            for (int nt = 0; nt < 4; ++nt)
                mrn[nt] = *(const f4*)(mg + k0 + 64 + (nt << 4) + (lg << 2));
        }
        // [B] swapped QK^T on K1[p]
        const unsigned char* Kc = K1 + (p << 13);
        f4 s[4];
        __builtin_amdgcn_s_setprio(1);
        #pragma unroll
        for (int nt = 0; nt < 4; ++nt) {
            const int kr = (nt << 4) + cx;
            const int mk = kr & 7;
            s[nt] = (f4){0.f, 0.f, 0.f, 0.f};
            #pragma unroll
            for (int ks = 0; ks < 2; ++ks) {
                const bf16x8 kb = *(const bf16x8*)(Kc + kr * 128 + (((((ks << 2) + lg)) ^ mk) << 4));
                s[nt] = mfma16(kb, qb[ks], s[nt]);
            }
        }
        __builtin_amdgcn_s_setprio(0);
        // [E] P = exp2(...); direct f4 attn store; cvt_pk + u64 Ps write (wave-private)
        #pragma unroll
        for (int nt = 0; nt < 4; ++nt) {
            f4 pv;
            #pragma unroll
            for (int r = 0; r < 4; ++r)
                pv[r] = fast_exp2(fmaf(s[nt][r], C2, fmaf(mrc[nt][r], M2, cofs)));
            *(f4*)(arow + k0 + (nt << 4) + (lg << 2)) = pv;
            const unsigned w0 = cvtpk_bf16(pv[0], pv[1]);
            const unsigned w1 = cvtpk_bf16(pv[2], pv[3]);
            const u64 packed = (u64)w0 | ((u64)w1 << 32);
            *(u64*)(Ps + (((wave << 4) + cx) * 128) +
                    ((unsigned)((nt << 5) + (lg << 3)) ^ psSwz)) = packed;
        }
        #pragma unroll
        for (int nt = 0; nt < 4; ++nt) mrc[nt] = mrn[nt];
        // [G] PV: pa from Ps (same wave, in-order DS), vb from Vs[p]
        __builtin_amdgcn_s_setprio(1);
        #pragma unroll
        for (int ks = 0; ks < 2; ++ks) {
            const bf16x8 pa = *(const bf16x8*)(Ps + (((wave << 4) + cx) * 128) +
                                ((unsigned)((ks << 6) + (lg << 4)) ^ psSwz));
            #pragma unroll
            for (int nt = 0; nt < 4; ++nt) {
                const int dr = (nt << 4) + cx;
                const bf16x8 vb = *(const bf16x8*)(Vs + (p << 13) + dr * 128 +
                                    (((((ks << 2) + lg)) ^ (dr & 7)) << 4));
                cacc[nt] = mfma16(pa, vb, cacc[nt]);
            }
        }
        __builtin_amdgcn_s_setprio(0);
        // drain stage(t+1)+mask; leave this tile's 4 stores in flight
        asm volatile("s_waitcnt vmcnt(4)" ::: "memory");
        __builtin_amdgcn_s_barrier();
    }

    // ---- ctx out: lane holds q = wave*16+lg*4+r, d = nt*16+cx ----
    #pragma unroll
    for (int nt = 0; nt < 4; ++nt)
        #pragma unroll
        for (int r = 0; r < 4; ++r) {
            const int srow = q0 + (wave << 4) + (lg << 2) + r;
            const int d = (h << 6) + (nt << 4) + cx;
            ctx_hi[((size_t)b * 2048 + srow) * 1024 + d] = f2bf(cacc[nt][r]);
        }
}

// ---------------- launcher ----------------
extern "C" void kernel_launch(void* const* d_in, const int* in_sizes, int n_in,
                              void* d_out, int out_size, void* d_ws, size_t ws_size,
                              hipStream_t stream)
{
    const float* v_in = (const float*)d_in[0];
    const float* k_in = (const float*)d_in[1];
    const float* q_in = (const float*)d_in[2];
    const float* mask = (const float*)d_in[3];
    const float* Wq = (const float*)d_in[4];
    const float* bq = (const float*)d_in[5];
    const float* Wk = (const float*)d_in[6];
    const float* bk = (const float*)d_in[7];
    const float* Wv = (const float*)d_in[8];
    const float* bv = (const float*)d_in[9];
    const float* Wo = (const float*)d_in[10];
    const float* bo = (const float*)d_in[11];

    float* out  = (float*)d_out;                    // [2,2048,1024]
    float* attn = out + (size_t)4194304;            // [2,16,2048,2048] = 512 MB

    unsigned char* ws = (unsigned char*)d_ws;       // 48 MB used
    unsigned short* wt     = (unsigned short*)(ws);                         // 8 MB (q,k,v,o)
    unsigned short* q_hi   = (unsigned short*)(ws + (size_t)(8)  * 1048576);
    unsigned short* k_hi   = (unsigned short*)(ws + (size_t)(16) * 1048576);
    unsigned short* v_hi   = (unsigned short*)(ws + (size_t)(24) * 1048576);
    unsigned short* ctx_hi = (unsigned short*)(ws + (size_t)(32) * 1048576);
    unsigned short* vT     = (unsigned short*)(ws + (size_t)(40) * 1048576); // [b,h,d,s]

    // dead scratch inside the attn output region (overwritten by attn_kernel later)
    unsigned short* a_hi   = (unsigned short*)(attn + (size_t)60 * 1048576);  // 24 MB

    prep_w_kernel<<<dim3(16, 16, 4), 256, 0, stream>>>(Wq, Wk, Wv, Wo, wt);
    prep_a_kernel<<<3072, 256, 0, stream>>>(q_in, k_in, v_in, a_hi);
    qkv_gemm_kernel<<<768, 256, 0, stream>>>(a_hi, wt, bq, bk, bv, q_hi, k_hi, v_hi);
    vtr_kernel<<<dim3(32, 32), 256, 0, stream>>>(v_hi, vT);
    attn_kernel<<<1024, 256, 0, stream>>>(q_hi, k_hi, vT, mask, attn, ctx_hi);
    out_gemm_kernel<<<256, 256, 0, stream>>>(ctx_hi, wt + (size_t)3 * 1048576, bo, out);
}

// Round 15
// 292.689 us; speedup vs baseline: 1.2750x; 1.2750x over previous
//
#include <hip/hip_runtime.h>
#include <cstdint>
#include <cstddef>

typedef __attribute__((ext_vector_type(4))) float f4;
typedef __attribute__((ext_vector_type(8))) short bf16x8;
typedef __attribute__((ext_vector_type(8))) unsigned short u16x8;
typedef unsigned long long u64;

// ---------------- helpers ----------------
__device__ __forceinline__ unsigned short f2bf(float x) {
    unsigned u = __float_as_uint(x);
    u += 0x7fffu + ((u >> 16) & 1u);
    return (unsigned short)(u >> 16);
}
__device__ __forceinline__ float bf2f(unsigned short h) {
    return __uint_as_float(((unsigned)h) << 16);
}
__device__ __forceinline__ unsigned cvtpk_bf16(float lo, float hi) {
    unsigned r;
    asm("v_cvt_pk_bf16_f32 %0, %1, %2" : "=v"(r) : "v"(lo), "v"(hi));
    return r;
}
__device__ __forceinline__ float fast_exp2(float x) { return __builtin_amdgcn_exp2f(x); }
__device__ __forceinline__ float fast_log2(float x) { return __builtin_amdgcn_logf(x); }
__device__ __forceinline__ void gll16(const void* g, void* l) {
    __builtin_amdgcn_global_load_lds(
        (const __attribute__((address_space(1))) unsigned int*)g,
        (__attribute__((address_space(3))) unsigned int*)l, 16, 0, 0);
}
__device__ __forceinline__ f4 mfma16(bf16x8 a, bf16x8 b, f4 c) {
    return __builtin_amdgcn_mfma_f32_16x16x32_bf16(a, b, c, 0, 0, 0);
}

// ---------------- weight prep: W[K][N] fp32 -> W^T[N][K] bf16 (hi only) ----------------
__global__ __launch_bounds__(256)
void prep_w_kernel(const float* __restrict__ Wq, const float* __restrict__ Wk,
                   const float* __restrict__ Wv, const float* __restrict__ Wo,
                   unsigned short* __restrict__ wt)   // 4 x 1048576
{
    const int w = blockIdx.z;
    const float* W = w == 0 ? Wq : (w == 1 ? Wk : (w == 2 ? Wv : Wo));
    unsigned short* hi = wt + (size_t)w * 1048576;

    const int kb = blockIdx.x << 6, nb = blockIdx.y << 6;
    __shared__ float T[64][68];
    const int tid = threadIdx.x;
    {
        const int r = tid >> 2, c0 = (tid & 3) << 4;
        const float* src = W + (size_t)(kb + r) * 1024 + nb + c0;
        *(f4*)&T[r][c0 + 0]  = *(const f4*)(src + 0);
        *(f4*)&T[r][c0 + 4]  = *(const f4*)(src + 4);
        *(f4*)&T[r][c0 + 8]  = *(const f4*)(src + 8);
        *(f4*)&T[r][c0 + 12] = *(const f4*)(src + 12);
    }
    __syncthreads();
    {
        const int n = tid & 63, ks = (tid >> 6) << 4;
        unsigned short vh[16];
        #pragma unroll
        for (int j = 0; j < 16; ++j) vh[j] = f2bf(T[ks + j][n]);
        const size_t dst = (size_t)(nb + n) * 1024 + kb + ks;
        *(u16x8*)(hi + dst)     = *(u16x8*)&vh[0];
        *(u16x8*)(hi + dst + 8) = *(u16x8*)&vh[8];
    }
}

// ---------------- activation prep: q/k/v fp32 -> bf16 ----------------
__global__ __launch_bounds__(256)
void prep_a_kernel(const float* __restrict__ q, const float* __restrict__ k,
                   const float* __restrict__ v, unsigned short* __restrict__ a_hi)
{
    const int gid = blockIdx.x * 256 + threadIdx.x;
    const int z = gid >> 18;
    const int rem = gid & 262143;
    const float* src = z == 0 ? q : (z == 1 ? k : v);
    const size_t off = (size_t)rem << 4;
    const float* s = src + off;
    unsigned short* hi = a_hi + ((size_t)z << 22) + off;
    float xs[16];
    *(f4*)&xs[0]  = *(const f4*)(s + 0);
    *(f4*)&xs[4]  = *(const f4*)(s + 4);
    *(f4*)&xs[8]  = *(const f4*)(s + 8);
    *(f4*)&xs[12] = *(const f4*)(s + 12);
    unsigned short hv[16];
    #pragma unroll
    for (int j = 0; j < 16; ++j) hv[j] = f2bf(xs[j]);
    *(u16x8*)(hi + 0) = *(u16x8*)&hv[0];
    *(u16x8*)(hi + 8) = *(u16x8*)&hv[8];
}

// ---------------- 1-term 128x128 GEMM core (plain bf16), BK=64, 32 KB LDS ----------------
// mode 1: head-split bf16 [b,h,s,d]; mode 2: fp32 [m][n];
// mode 3: head-split TRANSPOSED [b,h,d,s] via in-LDS 128x128 transpose (coalesced).
__device__ __forceinline__ void gemm1_core(
    const unsigned short* __restrict__ AH, const unsigned short* __restrict__ WH,
    const float* __restrict__ bias, int bm, int bn, int mode,
    unsigned short* __restrict__ o_hi, float* __restrict__ o_f32, unsigned char* lds)
{
    unsigned char* As = lds;            // [128 rows][128B k], swz (r&7)
    unsigned char* Bs = lds + 16384;

    const int tid = threadIdx.x, lane = tid & 63, wave = tid >> 6;
    const int wm = wave >> 1, wn = wave & 1;
    const int cx = lane & 15, lg = lane >> 4;
    const int l3 = lane >> 3, p3 = lane & 7;
    const int m0 = bm << 7, n0 = bn << 7;

    f4 acc[4][4];
    #pragma unroll
    for (int i = 0; i < 4; ++i)
        #pragma unroll
        for (int j = 0; j < 4; ++j) acc[i][j] = (f4){0.f, 0.f, 0.f, 0.f};

    #pragma unroll 1
    for (int k0 = 0; k0 < 1024; k0 += 64) {
        __syncthreads();
        #pragma unroll
        for (int c = 0; c < 4; ++c) {
            const int cb = (c << 2) + wave;
            const int row = (cb << 3) + l3;
            const int lgx = p3 ^ (row & 7);
            gll16(AH + (size_t)(m0 + row) * 1024 + k0 + (lgx << 3),
                  As + (cb << 10) + (lane << 4));
            gll16(WH + (size_t)(n0 + row) * 1024 + k0 + (lgx << 3),
                  Bs + (cb << 10) + (lane << 4));
        }
        __syncthreads();
        #pragma unroll
        for (int ks = 0; ks < 2; ++ks) {
            bf16x8 ah[4], bh[4];
            #pragma unroll
            for (int t = 0; t < 4; ++t) {
                const int r = (wm << 6) + (t << 4) + cx;
                ah[t] = *(const bf16x8*)(As + r * 128 + (((((ks << 2) + lg)) ^ (r & 7)) << 4));
                const int n = (wn << 6) + (t << 4) + cx;
                bh[t] = *(const bf16x8*)(Bs + n * 128 + (((((ks << 2) + lg)) ^ (n & 7)) << 4));
            }
            #pragma unroll
            for (int i = 0; i < 4; ++i)
                #pragma unroll
                for (int j = 0; j < 4; ++j)
                    acc[i][j] = mfma16(ah[i], bh[j], acc[i][j]);
        }
    }

    float bv4[4];
    #pragma unroll
    for (int j = 0; j < 4; ++j) bv4[j] = bias[n0 + (wn << 6) + (j << 4) + cx];

    if (mode == 3) {
        // ---- transpose epilogue: acc -> LDS T[128 s][128 d] (swz) -> vT[b,h,d,s] ----
        __syncthreads();                       // all waves done reading As/Bs
        unsigned short* T = (unsigned short*)lds;   // 128*128*2 = 32768 B exactly
        #pragma unroll
        for (int i = 0; i < 4; ++i)
            #pragma unroll
            for (int j = 0; j < 4; ++j) {
                const int dl = (wn << 6) + (j << 4) + cx;
                #pragma unroll
                for (int r = 0; r < 4; ++r) {
                    const int sl = (wm << 6) + (i << 4) + (lg << 2) + r;
                    T[sl * 128 + (dl ^ ((sl & 7) << 3))] = f2bf(acc[i][j][r] + bv4[j]);
                }
            }
        __syncthreads();
        const int b = m0 >> 11, s0g = m0 & 2047;
        const int dl = tid >> 1, sc = (tid & 1) << 6;
        const int hh = (n0 + dl) >> 6, d = (n0 + dl) & 63;
        unsigned short ov[64];
        #pragma unroll
        for (int j = 0; j < 64; ++j)
            ov[j] = T[(sc + j) * 128 + (dl ^ (((sc + j) & 7) << 3))];
        unsigned short* dst = o_hi + ((((size_t)(b * 16 + hh)) * 64 + d) << 11) + s0g + sc;
        #pragma unroll
        for (int c8 = 0; c8 < 8; ++c8)
            *(u16x8*)(dst + (c8 << 3)) = *(u16x8*)&ov[c8 << 3];
        return;
    }

    #pragma unroll
    for (int i = 0; i < 4; ++i)
        #pragma unroll
        for (int j = 0; j < 4; ++j) {
            const int n = n0 + (wn << 6) + (j << 4) + cx;
            const int mb = m0 + (wm << 6) + (i << 4) + (lg << 2);
            if (mode == 2) {
                #pragma unroll
                for (int r = 0; r < 4; ++r)
                    o_f32[(size_t)(mb + r) * 1024 + n] = acc[i][j][r] + bv4[j];
            } else {
                const int b = mb >> 11, hh = n >> 6, d = n & 63;
                #pragma unroll
                for (int r = 0; r < 4; ++r) {
                    const int s = (mb + r) & 2047;
                    o_hi[(((size_t)(b * 16 + hh)) * 2048 + s) * 64 + d] = f2bf(acc[i][j][r] + bv4[j]);
                }
            }
        }
}

__global__ __launch_bounds__(256)
void qkv_gemm_kernel(const unsigned short* __restrict__ a_hi,
                     const unsigned short* __restrict__ wt,
                     const float* __restrict__ bq, const float* __restrict__ bk,
                     const float* __restrict__ bv,
                     unsigned short* __restrict__ q_hi, unsigned short* __restrict__ k_hi,
                     unsigned short* __restrict__ vT)
{
    __shared__ __align__(16) unsigned char lds[32768];
    const int f = blockIdx.x;                     // 768, %8==0 -> bijective XCD swizzle
    const int id2 = (f & 7) * 96 + (f >> 3);
    const int z = id2 >> 8;
    const int rem = id2 & 255;
    const int bn = rem >> 5, bm = rem & 31;
    const unsigned short* AH = a_hi + ((size_t)z << 22);
    const unsigned short* WH = wt + (size_t)z * 1048576;
    const float* bias = z == 0 ? bq : (z == 1 ? bk : bv);
    unsigned short* ohi = z == 0 ? q_hi : (z == 1 ? k_hi : vT);
    gemm1_core(AH, WH, bias, bm, bn, (z == 2) ? 3 : 1, ohi, nullptr, lds);
}

__global__ __launch_bounds__(256)
void out_gemm_kernel(const unsigned short* __restrict__ ctx_hi,
                     const unsigned short* __restrict__ wt_o,
                     const float* __restrict__ bo, float* __restrict__ out)
{
    __shared__ __align__(16) unsigned char lds[32768];
    const int f = blockIdx.x;                     // 256
    const int id2 = (f & 7) * 32 + (f >> 3);
    const int bn = id2 >> 5, bm = id2 & 31;
    gemm1_core(ctx_hi, wt_o, bo, bm, bn, 2, nullptr, out, lds);
}

// ---------------- fused attention: swapped QK, gll16-staged K/V, 40 KB LDS ----------------
__global__ __launch_bounds__(256, 4)
void attn_kernel(const unsigned short* __restrict__ q_hi, const unsigned short* __restrict__ k_hi,
                 const unsigned short* __restrict__ vT, const float* __restrict__ mask,
                 float* __restrict__ attn, unsigned short* __restrict__ ctx_hi)
{
    __shared__ __align__(16) unsigned char lds[40960];
    unsigned char* K1 = lds;             // 2 x 8KB: K  [64 s][128B d], swz (s&7)
    unsigned char* Vs = lds + 16384;     // 2 x 8KB: V^T [64 d][128B s], swz (d&7)
    unsigned char* Ps = lds + 32768;     //     8KB: Q rows at prologue, then P [64 q][128B k]

    const int f = blockIdx.x;                       // 1024, %8==0 bijective
    const int swzf = (f & 7) * 128 + (f >> 3);
    const int bh = swzf >> 5;
    const int q0 = (swzf & 31) << 6;
    const int b = bh >> 4, h = bh & 15;
    const int tid = threadIdx.x, lane = tid & 63, wave = tid >> 6;
    const int cx = lane & 15, lg = lane >> 4;
    const int l3 = lane >> 3, p3 = lane & 7;
    const size_t base = (size_t)bh * 131072;        // k_hi [b,h,s,d] and vT [b,h,d,s]
    const float* mg = mask + (size_t)b * 2048;

    constexpr float C2   = 0.18033688011112042f;     // 0.125 * log2(e)
    constexpr float M2   = -1.4426950408889634e9f;   // -1e9 * log2(e)
    constexpr float MFIX = 4.0f;                     // fixed softmax shift (log2 domain)

    // ---- prologue: Q -> Ps, K tile0 -> K1[0], mask tile0 -> regs ----
    #pragma unroll
    for (int c = 0; c < 2; ++c) {
        const int cb = (c << 2) + wave;
        const int row = (cb << 3) + l3;
        const int lgx = p3 ^ (row & 7);
        gll16(q_hi + base + (size_t)(q0 + row) * 64 + (lgx << 3),
              Ps + (cb << 10) + (lane << 4));
        gll16(k_hi + base + (size_t)row * 64 + (lgx << 3),
              K1 + (cb << 10) + (lane << 4));
    }
    f4 mrc[4];
    #pragma unroll
    for (int nt = 0; nt < 4; ++nt) mrc[nt] = *(const f4*)(mg + (nt << 4) + (lg << 2));
    asm volatile("s_waitcnt vmcnt(0)" ::: "memory");
    __builtin_amdgcn_s_barrier();

    bf16x8 qb[2];
    {
        const int r = (wave << 4) + cx;
        const int mk = r & 7;
        #pragma unroll
        for (int ks = 0; ks < 2; ++ks)
            qb[ks] = *(const bf16x8*)(Ps + r * 128 + (((((ks << 2) + lg)) ^ mk) << 4));
    }

    // ---- pass 1: row sums. lane owns q = wave*16+cx; k = nt*16+lg*4+r ----
    float l4[4] = {0.f, 0.f, 0.f, 0.f};
    #pragma unroll 1
    for (int t = 0; t < 32; ++t) {
        const int p = t & 1;
        const int k0 = t << 6;
        f4 mrn[4];
        if (t < 31) {
            #pragma unroll
            for (int c = 0; c < 2; ++c) {
                const int cb = (c << 2) + wave;
                const int row = (cb << 3) + l3;
                const int lgx = p3 ^ (row & 7);
                gll16(k_hi + base + (size_t)(k0 + 64 + row) * 64 + (lgx << 3),
                      K1 + ((p ^ 1) << 13) + (cb << 10) + (lane << 4));
            }
            __builtin_amdgcn_sched_barrier(0);      // pin: gll16 before mask loads
            #pragma unroll
            for (int nt = 0; nt < 4; ++nt)
                mrn[nt] = *(const f4*)(mg + k0 + 64 + (nt << 4) + (lg << 2));
        }
        const unsigned char* Kc = K1 + (p << 13);
        __builtin_amdgcn_s_setprio(1);
        f4 sv[4];
        #pragma unroll
        for (int nt = 0; nt < 4; ++nt) {
            const int kr = (nt << 4) + cx;
            const int mk = kr & 7;
            f4 s = (f4){0.f, 0.f, 0.f, 0.f};
            #pragma unroll
            for (int ks = 0; ks < 2; ++ks) {
                const bf16x8 kb = *(const bf16x8*)(Kc + kr * 128 + (((((ks << 2) + lg)) ^ mk) << 4));
                s = mfma16(kb, qb[ks], s);
            }
            sv[nt] = s;
        }
        __builtin_amdgcn_s_setprio(0);
        #pragma unroll
        for (int nt = 0; nt < 4; ++nt)
            #pragma unroll
            for (int r = 0; r < 4; ++r)
                l4[nt] += fast_exp2(fmaf(sv[nt][r], C2, fmaf(mrc[nt][r], M2, -MFIX)));
        #pragma unroll
        for (int nt = 0; nt < 4; ++nt) mrc[nt] = mrn[nt];
        asm volatile("s_waitcnt vmcnt(4)" ::: "memory");
        __builtin_amdgcn_s_barrier();
    }
    float ssum = (l4[0] + l4[1]) + (l4[2] + l4[3]);
    ssum += __shfl_xor(ssum, 16);
    ssum += __shfl_xor(ssum, 32);
    const float cofs = -MFIX - fast_log2(ssum);      // P = exp2(logit2 + m*M2 + cofs)

    // ---- pass 2 prologue: K(0) -> K1[0], V(0) -> Vs[0], mask(0) -> regs ----
    #pragma unroll
    for (int c = 0; c < 2; ++c) {
        const int cb = (c << 2) + wave;
        const int row = (cb << 3) + l3;
        const int lgx = p3 ^ (row & 7);
        gll16(k_hi + base + (size_t)row * 64 + (lgx << 3),
              K1 + (cb << 10) + (lane << 4));
        gll16(vT + base + ((size_t)row << 11) + (lgx << 3),
              Vs + (cb << 10) + (lane << 4));
    }
    #pragma unroll
    for (int nt = 0; nt < 4; ++nt) mrc[nt] = *(const f4*)(mg + (nt << 4) + (lg << 2));
    asm volatile("s_waitcnt vmcnt(0)" ::: "memory");
    __builtin_amdgcn_s_barrier();

    f4 cacc[4];
    #pragma unroll
    for (int nt = 0; nt < 4; ++nt) cacc[nt] = (f4){0.f, 0.f, 0.f, 0.f};

    float* arow = attn + ((size_t)bh * 2048 + q0 + (wave << 4) + cx) * 2048;
    const unsigned psSwz = (unsigned)((cx & 7) << 4);

    #pragma unroll 1
    for (int t = 0; t < 32; ++t) {
        const int p = t & 1;
        const int k0 = t << 6;
        // [A] stage K(t+1), V(t+1) via gll16; mask(t+1) -> regs   (8 vm ops)
        f4 mrn[4];
        if (t < 31) {
            #pragma unroll
            for (int c = 0; c < 2; ++c) {
                const int cb = (c << 2) + wave;
                const int row = (cb << 3) + l3;
                const int lgx = p3 ^ (row & 7);
                gll16(k_hi + base + (size_t)(k0 + 64 + row) * 64 + (lgx << 3),
                      K1 + ((p ^ 1) << 13) + (cb << 10) + (lane << 4));
                gll16(vT + base + ((size_t)row << 11) + k0 + 64 + (lgx << 3),
                      Vs + ((p ^ 1) << 13) + (cb << 10) + (lane << 4));
            }
            __builtin_amdgcn_sched_barrier(0);
            #pragma unroll
            for (int nt = 0; nt < 4; ++nt)
                mrn[nt] = *(const f4*)(mg + k0 + 64 + (nt << 4) + (lg << 2));
        }
        // [B] swapped QK^T on K1[p]
        const unsigned char* Kc = K1 + (p << 13);
        f4 s[4];
        __builtin_amdgcn_s_setprio(1);
        #pragma unroll
        for (int nt = 0; nt < 4; ++nt) {
            const int kr = (nt << 4) + cx;
            const int mk = kr & 7;
            s[nt] = (f4){0.f, 0.f, 0.f, 0.f};
            #pragma unroll
            for (int ks = 0; ks < 2; ++ks) {
                const bf16x8 kb = *(const bf16x8*)(Kc + kr * 128 + (((((ks << 2) + lg)) ^ mk) << 4));
                s[nt] = mfma16(kb, qb[ks], s[nt]);
            }
        }
        __builtin_amdgcn_s_setprio(0);
        // [E] P = exp2(...); direct f4 attn store; cvt_pk + u64 Ps write (wave-private)
        #pragma unroll
        for (int nt = 0; nt < 4; ++nt) {
            f4 pv;
            #pragma unroll
            for (int r = 0; r < 4; ++r)
                pv[r] = fast_exp2(fmaf(s[nt][r], C2, fmaf(mrc[nt][r], M2, cofs)));
            *(f4*)(arow + k0 + (nt << 4) + (lg << 2)) = pv;
            const unsigned w0 = cvtpk_bf16(pv[0], pv[1]);
            const unsigned w1 = cvtpk_bf16(pv[2], pv[3]);
            const u64 packed = (u64)w0 | ((u64)w1 << 32);
            *(u64*)(Ps + (((wave << 4) + cx) * 128) +
                    ((unsigned)((nt << 5) + (lg << 3)) ^ psSwz)) = packed;
        }
        #pragma unroll
        for (int nt = 0; nt < 4; ++nt) mrc[nt] = mrn[nt];
        // [G] PV: pa from Ps (same wave, in-order DS), vb from Vs[p]
        __builtin_amdgcn_s_setprio(1);
        #pragma unroll
        for (int ks = 0; ks < 2; ++ks) {
            const bf16x8 pa = *(const bf16x8*)(Ps + (((wave << 4) + cx) * 128) +
                                ((unsigned)((ks << 6) + (lg << 4)) ^ psSwz));
            #pragma unroll
            for (int nt = 0; nt < 4; ++nt) {
                const int dr = (nt << 4) + cx;
                const bf16x8 vb = *(const bf16x8*)(Vs + (p << 13) + dr * 128 +
                                    (((((ks << 2) + lg)) ^ (dr & 7)) << 4));
                cacc[nt] = mfma16(pa, vb, cacc[nt]);
            }
        }
        __builtin_amdgcn_s_setprio(0);
        // drain stage(t+1)+mask (8 oldest); leave this tile's 4 stores in flight
        asm volatile("s_waitcnt vmcnt(4)" ::: "memory");
        __builtin_amdgcn_s_barrier();
    }

    // ---- ctx out: lane holds q = wave*16+lg*4+r, d = nt*16+cx ----
    #pragma unroll
    for (int nt = 0; nt < 4; ++nt)
        #pragma unroll
        for (int r = 0; r < 4; ++r) {
            const int srow = q0 + (wave << 4) + (lg << 2) + r;
            const int d = (h << 6) + (nt << 4) + cx;
            ctx_hi[((size_t)b * 2048 + srow) * 1024 + d] = f2bf(cacc[nt][r]);
        }
}

// ---------------- launcher ----------------
extern "C" void kernel_launch(void* const* d_in, const int* in_sizes, int n_in,
                              void* d_out, int out_size, void* d_ws, size_t ws_size,
                              hipStream_t stream)
{
    const float* v_in = (const float*)d_in[0];
    const float* k_in = (const float*)d_in[1];
    const float* q_in = (const float*)d_in[2];
    const float* mask = (const float*)d_in[3];
    const float* Wq = (const float*)d_in[4];
    const float* bq = (const float*)d_in[5];
    const float* Wk = (const float*)d_in[6];
    const float* bk = (const float*)d_in[7];
    const float* Wv = (const float*)d_in[8];
    const float* bv = (const float*)d_in[9];
    const float* Wo = (const float*)d_in[10];
    const float* bo = (const float*)d_in[11];

    float* out  = (float*)d_out;                    // [2,2048,1024]
    float* attn = out + (size_t)4194304;            // [2,16,2048,2048] = 512 MB

    unsigned char* ws = (unsigned char*)d_ws;       // 40 MB used
    unsigned short* wt     = (unsigned short*)(ws);                         // 8 MB (q,k,v,o)
    unsigned short* q_hi   = (unsigned short*)(ws + (size_t)(8)  * 1048576);
    unsigned short* k_hi   = (unsigned short*)(ws + (size_t)(16) * 1048576);
    unsigned short* vT     = (unsigned short*)(ws + (size_t)(24) * 1048576); // [b,h,d,s]
    unsigned short* ctx_hi = (unsigned short*)(ws + (size_t)(32) * 1048576);

    // dead scratch inside the attn output region (overwritten by attn_kernel later)
    unsigned short* a_hi   = (unsigned short*)(attn + (size_t)60 * 1048576);  // 24 MB

    prep_w_kernel<<<dim3(16, 16, 4), 256, 0, stream>>>(Wq, Wk, Wv, Wo, wt);
    prep_a_kernel<<<3072, 256, 0, stream>>>(q_in, k_in, v_in, a_hi);
    qkv_gemm_kernel<<<768, 256, 0, stream>>>(a_hi, wt, bq, bk, bv, q_hi, k_hi, vT);
    attn_kernel<<<1024, 256, 0, stream>>>(q_hi, k_hi, vT, mask, attn, ctx_hi);
    out_gemm_kernel<<<256, 256, 0, stream>>>(ctx_hi, wt + (size_t)3 * 1048576, bo, out);
}

// Round 16
// 283.137 us; speedup vs baseline: 1.3180x; 1.0337x over previous
//
#include <hip/hip_runtime.h>
#include <cstdint>
#include <cstddef>

typedef __attribute__((ext_vector_type(4))) float f4;
typedef __attribute__((ext_vector_type(8))) short bf16x8;
typedef __attribute__((ext_vector_type(8))) unsigned short u16x8;
typedef unsigned long long u64;

// ---------------- helpers ----------------
__device__ __forceinline__ unsigned short f2bf(float x) {
    unsigned u = __float_as_uint(x);
    u += 0x7fffu + ((u >> 16) & 1u);
    return (unsigned short)(u >> 16);
}
__device__ __forceinline__ float bf2f(unsigned short h) {
    return __uint_as_float(((unsigned)h) << 16);
}
__device__ __forceinline__ unsigned cvtpk_bf16(float lo, float hi) {
    unsigned r;
    asm("v_cvt_pk_bf16_f32 %0, %1, %2" : "=v"(r) : "v"(lo), "v"(hi));
    return r;
}
__device__ __forceinline__ float fast_exp2(float x) { return __builtin_amdgcn_exp2f(x); }
__device__ __forceinline__ float fast_log2(float x) { return __builtin_amdgcn_logf(x); }
__device__ __forceinline__ void gll16(const void* g, void* l) {
    __builtin_amdgcn_global_load_lds(
        (const __attribute__((address_space(1))) unsigned int*)g,
        (__attribute__((address_space(3))) unsigned int*)l, 16, 0, 0);
}
__device__ __forceinline__ f4 mfma16(bf16x8 a, bf16x8 b, f4 c) {
    return __builtin_amdgcn_mfma_f32_16x16x32_bf16(a, b, c, 0, 0, 0);
}

// ---------------- weight prep: W[K][N] fp32 -> W^T[N][K] bf16 (hi only) ----------------
__global__ __launch_bounds__(256)
void prep_w_kernel(const float* __restrict__ Wq, const float* __restrict__ Wk,
                   const float* __restrict__ Wv, const float* __restrict__ Wo,
                   unsigned short* __restrict__ wt)   // 4 x 1048576
{
    const int w = blockIdx.z;
    const float* W = w == 0 ? Wq : (w == 1 ? Wk : (w == 2 ? Wv : Wo));
    unsigned short* hi = wt + (size_t)w * 1048576;

    const int kb = blockIdx.x << 6, nb = blockIdx.y << 6;
    __shared__ float T[64][68];
    const int tid = threadIdx.x;
    {
        const int r = tid >> 2, c0 = (tid & 3) << 4;
        const float* src = W + (size_t)(kb + r) * 1024 + nb + c0;
        *(f4*)&T[r][c0 + 0]  = *(const f4*)(src + 0);
        *(f4*)&T[r][c0 + 4]  = *(const f4*)(src + 4);
        *(f4*)&T[r][c0 + 8]  = *(const f4*)(src + 8);
        *(f4*)&T[r][c0 + 12] = *(const f4*)(src + 12);
    }
    __syncthreads();
    {
        const int n = tid & 63, ks = (tid >> 6) << 4;
        unsigned short vh[16];
        #pragma unroll
        for (int j = 0; j < 16; ++j) vh[j] = f2bf(T[ks + j][n]);
        const size_t dst = (size_t)(nb + n) * 1024 + kb + ks;
        *(u16x8*)(hi + dst)     = *(u16x8*)&vh[0];
        *(u16x8*)(hi + dst + 8) = *(u16x8*)&vh[8];
    }
}

// ---------------- V transpose: v_hi [b,h,s,d] -> vT [b,h,d,s] ----------------
__global__ __launch_bounds__(256)
void vtr_kernel(const unsigned short* __restrict__ v_hi, unsigned short* __restrict__ vT)
{
    __shared__ unsigned short T[64][80];   // row stride 160B (16B multiple)
    const int bh = blockIdx.y;
    const int s0 = blockIdx.x << 6;
    const int tid = threadIdx.x;
    const size_t base = (size_t)bh * 131072;
    {
        const int s = tid >> 2, dq = (tid & 3) << 4;
        const unsigned short* src = v_hi + base + (size_t)(s0 + s) * 64 + dq;
        u16x8 a = *(const u16x8*)src;
        u16x8 b = *(const u16x8*)(src + 8);
        *(u16x8*)&T[s][dq]     = a;
        *(u16x8*)&T[s][dq + 8] = b;
    }
    __syncthreads();
    {
        const int d = tid >> 2, sq = (tid & 3) << 4;
        unsigned short o[16];
        #pragma unroll
        for (int j = 0; j < 16; ++j) o[j] = T[sq + j][d];
        unsigned short* dst = vT + base + ((size_t)d << 11) + s0 + sq;
        *(u16x8*)dst       = *(u16x8*)&o[0];
        *(u16x8*)(dst + 8) = *(u16x8*)&o[8];
    }
}

// ---------------- qkv GEMM: fp32 A converted in-kernel, BK=64, 32 KB LDS ----------------
// C[4096][1024] = Af32 @ W^T' + bias -> head-split bf16 [b,h,s,d].
__global__ __launch_bounds__(256)
void qkv_gemm_kernel(const float* __restrict__ q_in, const float* __restrict__ k_in,
                     const float* __restrict__ v_in,
                     const unsigned short* __restrict__ wt,
                     const float* __restrict__ bq, const float* __restrict__ bk,
                     const float* __restrict__ bv,
                     unsigned short* __restrict__ q_hi, unsigned short* __restrict__ k_hi,
                     unsigned short* __restrict__ v_hi)
{
    __shared__ __align__(16) unsigned char lds[32768];
    unsigned char* As = lds;            // [128 rows][128B k], swz (r&7)
    unsigned char* Bs = lds + 16384;

    const int f = blockIdx.x;                     // 768, %8==0 -> bijective XCD swizzle
    const int id2 = (f & 7) * 96 + (f >> 3);
    const int z = id2 >> 8;
    const int rem = id2 & 255;
    const int bn = rem >> 5, bm = rem & 31;

    const float* AF = z == 0 ? q_in : (z == 1 ? k_in : v_in);
    const unsigned short* WH = wt + (size_t)z * 1048576;
    const float* bias = z == 0 ? bq : (z == 1 ? bk : bv);
    unsigned short* ohi = z == 0 ? q_hi : (z == 1 ? k_hi : v_hi);

    const int tid = threadIdx.x, lane = tid & 63, wave = tid >> 6;
    const int wm = wave >> 1, wn = wave & 1;
    const int cx = lane & 15, lg = lane >> 4;
    const int l3 = lane >> 3, p3 = lane & 7;
    const int m0 = bm << 7, n0 = bn << 7;

    f4 acc[4][4];
    #pragma unroll
    for (int i = 0; i < 4; ++i)
        #pragma unroll
        for (int j = 0; j < 4; ++j) acc[i][j] = (f4){0.f, 0.f, 0.f, 0.f};

    #pragma unroll 1
    for (int k0 = 0; k0 < 1024; k0 += 64) {
        __syncthreads();
        // B: 4 gll16 (bf16 weights, pre-swizzled source)
        #pragma unroll
        for (int c = 0; c < 4; ++c) {
            const int cb = (c << 2) + wave;
            const int row = (cb << 3) + l3;
            const int lgx = p3 ^ (row & 7);
            gll16(WH + (size_t)(n0 + row) * 1024 + k0 + (lgx << 3),
                  Bs + (cb << 10) + (lane << 4));
        }
        // A: fp32 coalesced f4 loads -> cvt_pk -> swizzled ds_write_b64
        #pragma unroll
        for (int c = 0; c < 8; ++c) {
            const int g = (c << 8) + tid;            // 0..2047
            const int row = g >> 4;                  // 0..127
            const int k4 = g & 15;                   // 4-float unit within 64
            const f4 av = *(const f4*)(AF + (size_t)(m0 + row) * 1024 + k0 + (k4 << 2));
            const unsigned w0 = cvtpk_bf16(av[0], av[1]);
            const unsigned w1 = cvtpk_bf16(av[2], av[3]);
            const u64 pk = (u64)w0 | ((u64)w1 << 32);
            *(u64*)(As + row * 128 + ((((k4 >> 1) ^ (row & 7)) << 4) | ((k4 & 1) << 3))) = pk;
        }
        __syncthreads();
        #pragma unroll
        for (int ks = 0; ks < 2; ++ks) {
            bf16x8 ah[4], bh[4];
            #pragma unroll
            for (int t = 0; t < 4; ++t) {
                const int r = (wm << 6) + (t << 4) + cx;
                ah[t] = *(const bf16x8*)(As + r * 128 + (((((ks << 2) + lg)) ^ (r & 7)) << 4));
                const int n = (wn << 6) + (t << 4) + cx;
                bh[t] = *(const bf16x8*)(Bs + n * 128 + (((((ks << 2) + lg)) ^ (n & 7)) << 4));
            }
            #pragma unroll
            for (int i = 0; i < 4; ++i)
                #pragma unroll
                for (int j = 0; j < 4; ++j)
                    acc[i][j] = mfma16(ah[i], bh[j], acc[i][j]);
        }
    }

    float bv4[4];
    #pragma unroll
    for (int j = 0; j < 4; ++j) bv4[j] = bias[n0 + (wn << 6) + (j << 4) + cx];

    #pragma unroll
    for (int i = 0; i < 4; ++i)
        #pragma unroll
        for (int j = 0; j < 4; ++j) {
            const int n = n0 + (wn << 6) + (j << 4) + cx;
            const int mb = m0 + (wm << 6) + (i << 4) + (lg << 2);
            const int b = mb >> 11, hh = n >> 6, d = n & 63;
            #pragma unroll
            for (int r = 0; r < 4; ++r) {
                const int s = (mb + r) & 2047;
                ohi[(((size_t)(b * 16 + hh)) * 2048 + s) * 64 + d] = f2bf(acc[i][j][r] + bv4[j]);
            }
        }
}

// ---------------- out GEMM: bf16 A (ctx), fp32 out, BK=64, 32 KB LDS ----------------
__global__ __launch_bounds__(256)
void out_gemm_kernel(const unsigned short* __restrict__ AH,
                     const unsigned short* __restrict__ wt_o,
                     const float* __restrict__ bo, float* __restrict__ out)
{
    __shared__ __align__(16) unsigned char lds[32768];
    unsigned char* As = lds;
    unsigned char* Bs = lds + 16384;

    const int f = blockIdx.x;                     // 256
    const int id2 = (f & 7) * 32 + (f >> 3);
    const int bn = id2 >> 5, bm = id2 & 31;

    const int tid = threadIdx.x, lane = tid & 63, wave = tid >> 6;
    const int wm = wave >> 1, wn = wave & 1;
    const int cx = lane & 15, lg = lane >> 4;
    const int l3 = lane >> 3, p3 = lane & 7;
    const int m0 = bm << 7, n0 = bn << 7;

    f4 acc[4][4];
    #pragma unroll
    for (int i = 0; i < 4; ++i)
        #pragma unroll
        for (int j = 0; j < 4; ++j) acc[i][j] = (f4){0.f, 0.f, 0.f, 0.f};

    #pragma unroll 1
    for (int k0 = 0; k0 < 1024; k0 += 64) {
        __syncthreads();
        #pragma unroll
        for (int c = 0; c < 4; ++c) {
            const int cb = (c << 2) + wave;
            const int row = (cb << 3) + l3;
            const int lgx = p3 ^ (row & 7);
            gll16(AH + (size_t)(m0 + row) * 1024 + k0 + (lgx << 3),
                  As + (cb << 10) + (lane << 4));
            gll16(wt_o + (size_t)(n0 + row) * 1024 + k0 + (lgx << 3),
                  Bs + (cb << 10) + (lane << 4));
        }
        __syncthreads();
        #pragma unroll
        for (int ks = 0; ks < 2; ++ks) {
            bf16x8 ah[4], bh[4];
            #pragma unroll
            for (int t = 0; t < 4; ++t) {
                const int r = (wm << 6) + (t << 4) + cx;
                ah[t] = *(const bf16x8*)(As + r * 128 + (((((ks << 2) + lg)) ^ (r & 7)) << 4));
                const int n = (wn << 6) + (t << 4) + cx;
                bh[t] = *(const bf16x8*)(Bs + n * 128 + (((((ks << 2) + lg)) ^ (n & 7)) << 4));
            }
            #pragma unroll
            for (int i = 0; i < 4; ++i)
                #pragma unroll
                for (int j = 0; j < 4; ++j)
                    acc[i][j] = mfma16(ah[i], bh[j], acc[i][j]);
        }
    }

    float bv4[4];
    #pragma unroll
    for (int j = 0; j < 4; ++j) bv4[j] = bo[n0 + (wn << 6) + (j << 4) + cx];

    #pragma unroll
    for (int i = 0; i < 4; ++i)
        #pragma unroll
        for (int j = 0; j < 4; ++j) {
            const int n = n0 + (wn << 6) + (j << 4) + cx;
            const int mb = m0 + (wm << 6) + (i << 4) + (lg << 2);
            #pragma unroll
            for (int r = 0; r < 4; ++r)
                out[(size_t)(mb + r) * 1024 + n] = acc[i][j][r] + bv4[j];
        }
}

// ---------------- fused attention (R12-exact): swapped QK, gll16 K/V, coalesced P store ----------------
__global__ __launch_bounds__(256, 4)
void attn_kernel(const unsigned short* __restrict__ q_hi, const unsigned short* __restrict__ k_hi,
                 const unsigned short* __restrict__ vT, const float* __restrict__ mask,
                 float* __restrict__ attn, unsigned short* __restrict__ ctx_hi)
{
    __shared__ __align__(16) unsigned char lds[40960];
    unsigned char* K1 = lds;             // 2 x 8KB: K  [64 s][128B d], swz (s&7)
    unsigned char* Vs = lds + 16384;     // 2 x 8KB: V^T [64 d][128B s], swz (d&7)
    unsigned char* Ps = lds + 32768;     //     8KB: Q rows at prologue, then P [64 q][128B k]

    const int f = blockIdx.x;                       // 1024, %8==0 bijective
    const int swzf = (f & 7) * 128 + (f >> 3);
    const int bh = swzf >> 5;
    const int q0 = (swzf & 31) << 6;
    const int b = bh >> 4, h = bh & 15;
    const int tid = threadIdx.x, lane = tid & 63, wave = tid >> 6;
    const int cx = lane & 15, lg = lane >> 4;
    const int l3 = lane >> 3, p3 = lane & 7;
    const size_t base = (size_t)bh * 131072;        // k_hi [b,h,s,d] and vT [b,h,d,s]
    const float* mg = mask + (size_t)b * 2048;

    constexpr float C2   = 0.18033688011112042f;     // 0.125 * log2(e)
    constexpr float M2   = -1.4426950408889634e9f;   // -1e9 * log2(e)
    constexpr float MFIX = 4.0f;                     // fixed softmax shift (log2 domain)

    // ---- prologue: Q -> Ps, K tile0 -> K1[0], mask tile0 -> regs ----
    #pragma unroll
    for (int c = 0; c < 2; ++c) {
        const int cb = (c << 2) + wave;
        const int row = (cb << 3) + l3;
        const int lgx = p3 ^ (row & 7);
        gll16(q_hi + base + (size_t)(q0 + row) * 64 + (lgx << 3),
              Ps + (cb << 10) + (lane << 4));
        gll16(k_hi + base + (size_t)row * 64 + (lgx << 3),
              K1 + (cb << 10) + (lane << 4));
    }
    f4 mrc[4];
    #pragma unroll
    for (int nt = 0; nt < 4; ++nt) mrc[nt] = *(const f4*)(mg + (nt << 4) + (lg << 2));
    asm volatile("s_waitcnt vmcnt(0)" ::: "memory");
    __builtin_amdgcn_s_barrier();

    bf16x8 qb[2];
    {
        const int r = (wave << 4) + cx;
        const int mk = r & 7;
        #pragma unroll
        for (int ks = 0; ks < 2; ++ks)
            qb[ks] = *(const bf16x8*)(Ps + r * 128 + (((((ks << 2) + lg)) ^ mk) << 4));
    }

    // ---- pass 1: row sums. lane owns q = wave*16+cx; k = nt*16+lg*4+r ----
    float l4[4] = {0.f, 0.f, 0.f, 0.f};             // 4 independent chains
    #pragma unroll 1
    for (int t = 0; t < 32; ++t) {
        const int p = t & 1;
        const int k0 = t << 6;
        f4 mrn[4];
        if (t < 31) {
            #pragma unroll
            for (int c = 0; c < 2; ++c) {
                const int cb = (c << 2) + wave;
                const int row = (cb << 3) + l3;
                const int lgx = p3 ^ (row & 7);
                gll16(k_hi + base + (size_t)(k0 + 64 + row) * 64 + (lgx << 3),
                      K1 + ((p ^ 1) << 13) + (cb << 10) + (lane << 4));
            }
            __builtin_amdgcn_sched_barrier(0);      // pin: gll16 before mask loads
            #pragma unroll
            for (int nt = 0; nt < 4; ++nt)
                mrn[nt] = *(const f4*)(mg + k0 + 64 + (nt << 4) + (lg << 2));
        }
        const unsigned char* Kc = K1 + (p << 13);
        __builtin_amdgcn_s_setprio(1);
        f4 sv[4];
        #pragma unroll
        for (int nt = 0; nt < 4; ++nt) {
            const int kr = (nt << 4) + cx;
            const int mk = kr & 7;
            f4 s = (f4){0.f, 0.f, 0.f, 0.f};
            #pragma unroll
            for (int ks = 0; ks < 2; ++ks) {
                const bf16x8 kb = *(const bf16x8*)(Kc + kr * 128 + (((((ks << 2) + lg)) ^ mk) << 4));
                s = mfma16(kb, qb[ks], s);
            }
            sv[nt] = s;
        }
        __builtin_amdgcn_s_setprio(0);
        #pragma unroll
        for (int nt = 0; nt < 4; ++nt)
            #pragma unroll
            for (int r = 0; r < 4; ++r)
                l4[nt] += fast_exp2(fmaf(sv[nt][r], C2, fmaf(mrc[nt][r], M2, -MFIX)));
        #pragma unroll
        for (int nt = 0; nt < 4; ++nt) mrc[nt] = mrn[nt];
        asm volatile("s_waitcnt vmcnt(4)" ::: "memory");
        __builtin_amdgcn_s_barrier();
    }
    float ssum = (l4[0] + l4[1]) + (l4[2] + l4[3]);
    ssum += __shfl_xor(ssum, 16);
    ssum += __shfl_xor(ssum, 32);
    const float cofs = -MFIX - fast_log2(ssum);      // P = exp2(logit2 + m*M2 + cofs)

    // ---- pass 2 prologue: K(0) -> K1[0], V(0) -> Vs[0], mask(0) -> regs ----
    #pragma unroll
    for (int c = 0; c < 2; ++c) {
        const int cb = (c << 2) + wave;
        const int row = (cb << 3) + l3;
        const int lgx = p3 ^ (row & 7);
        gll16(k_hi + base + (size_t)row * 64 + (lgx << 3),
              K1 + (cb << 10) + (lane << 4));
        gll16(vT + base + ((size_t)row << 11) + (lgx << 3),
              Vs + (cb << 10) + (lane << 4));
    }
    #pragma unroll
    for (int nt = 0; nt < 4; ++nt) mrc[nt] = *(const f4*)(mg + (nt << 4) + (lg << 2));
    asm volatile("s_waitcnt vmcnt(0)" ::: "memory");
    __builtin_amdgcn_s_barrier();

    f4 cacc[4];
    #pragma unroll
    for (int nt = 0; nt < 4; ++nt) cacc[nt] = (f4){0.f, 0.f, 0.f, 0.f};

    float* ablk = attn + ((size_t)bh * 2048 + q0) * 2048;   // block's attn tile base
    const unsigned psSwz = (unsigned)((cx & 7) << 4);

    #pragma unroll 1
    for (int t = 0; t < 32; ++t) {
        const int p = t & 1;
        const int k0 = t << 6;
        // [A] stage K(t+1), V(t+1) via gll16; mask(t+1) -> regs   (8 vm ops)
        f4 mrn[4];
        if (t < 31) {
            #pragma unroll
            for (int c = 0; c < 2; ++c) {
                const int cb = (c << 2) + wave;
                const int row = (cb << 3) + l3;
                const int lgx = p3 ^ (row & 7);
                gll16(k_hi + base + (size_t)(k0 + 64 + row) * 64 + (lgx << 3),
                      K1 + ((p ^ 1) << 13) + (cb << 10) + (lane << 4));
                gll16(vT + base + ((size_t)row << 11) + k0 + 64 + (lgx << 3),
                      Vs + ((p ^ 1) << 13) + (cb << 10) + (lane << 4));
            }
            #pragma unroll
            for (int nt = 0; nt < 4; ++nt)
                mrn[nt] = *(const f4*)(mg + k0 + 64 + (nt << 4) + (lg << 2));
        }
        // [B] swapped QK^T on K1[p]
        const unsigned char* Kc = K1 + (p << 13);
        f4 s[4];
        __builtin_amdgcn_s_setprio(1);
        #pragma unroll
        for (int nt = 0; nt < 4; ++nt) {
            const int kr = (nt << 4) + cx;
            const int mk = kr & 7;
            s[nt] = (f4){0.f, 0.f, 0.f, 0.f};
            #pragma unroll
            for (int ks = 0; ks < 2; ++ks) {
                const bf16x8 kb = *(const bf16x8*)(Kc + kr * 128 + (((((ks << 2) + lg)) ^ mk) << 4));
                s[nt] = mfma16(kb, qb[ks], s[nt]);
            }
        }
        __builtin_amdgcn_s_setprio(0);
        // [E] P = exp2(...); u64 Ps write (wave-private rows)
        #pragma unroll
        for (int nt = 0; nt < 4; ++nt) {
            f4 pv;
            #pragma unroll
            for (int r = 0; r < 4; ++r)
                pv[r] = fast_exp2(fmaf(s[nt][r], C2, fmaf(mrc[nt][r], M2, cofs)));
            const unsigned w0 = cvtpk_bf16(pv[0], pv[1]);
            const unsigned w1 = cvtpk_bf16(pv[2], pv[3]);
            const u64 packed = (u64)w0 | ((u64)w1 << 32);
            *(u64*)(Ps + (((wave << 4) + cx) * 128) +
                    ((unsigned)((nt << 5) + (lg << 3)) ^ psSwz)) = packed;
        }
        #pragma unroll
        for (int nt = 0; nt < 4; ++nt) mrc[nt] = mrn[nt];
        // [E2] coalesced attn store via Ps readback: 4 rows x 256B per instruction
        #pragma unroll
        for (int i = 0; i < 4; ++i) {
            const int row = (wave << 4) + (i << 2) + (lane >> 4);   // this wave's rows
            const unsigned kb = (unsigned)((lane & 15) << 3);       // u64 = 4 k values
            const u64 pk = *(const u64*)(Ps + row * 128 + (kb ^ ((unsigned)(row & 7) << 4)));
            f4 ov;
            ov[0] = bf2f((unsigned short)(pk));
            ov[1] = bf2f((unsigned short)(pk >> 16));
            ov[2] = bf2f((unsigned short)(pk >> 32));
            ov[3] = bf2f((unsigned short)(pk >> 48));
            *(f4*)(ablk + (size_t)row * 2048 + k0 + ((lane & 15) << 2)) = ov;
        }
        // [G] PV: pa from Ps (same wave, in-order DS), vb from Vs[p]
        __builtin_amdgcn_s_setprio(1);
        #pragma unroll
        for (int ks = 0; ks < 2; ++ks) {
            const bf16x8 pa = *(const bf16x8*)(Ps + (((wave << 4) + cx) * 128) +
                                ((unsigned)((ks << 6) + (lg << 4)) ^ psSwz));
            #pragma unroll
            for (int nt = 0; nt < 4; ++nt) {
                const int dr = (nt << 4) + cx;
                const bf16x8 vb = *(const bf16x8*)(Vs + (p << 13) + dr * 128 +
                                    (((((ks << 2) + lg)) ^ (dr & 7)) << 4));
                cacc[nt] = mfma16(pa, vb, cacc[nt]);
            }
        }
        __builtin_amdgcn_s_setprio(0);
        // drain stage(t+1)+mask; leave this tile's 4 stores in flight
        asm volatile("s_waitcnt vmcnt(4)" ::: "memory");
        __builtin_amdgcn_s_barrier();
    }

    // ---- ctx out: lane holds q = wave*16+lg*4+r, d = nt*16+cx ----
    #pragma unroll
    for (int nt = 0; nt < 4; ++nt)
        #pragma unroll
        for (int r = 0; r < 4; ++r) {
            const int srow = q0 + (wave << 4) + (lg << 2) + r;
            const int d = (h << 6) + (nt << 4) + cx;
            ctx_hi[((size_t)b * 2048 + srow) * 1024 + d] = f2bf(cacc[nt][r]);
        }
}

// ---------------- launcher ----------------
extern "C" void kernel_launch(void* const* d_in, const int* in_sizes, int n_in,
                              void* d_out, int out_size, void* d_ws, size_t ws_size,
                              hipStream_t stream)
{
    const float* v_in = (const float*)d_in[0];
    const float* k_in = (const float*)d_in[1];
    const float* q_in = (const float*)d_in[2];
    const float* mask = (const float*)d_in[3];
    const float* Wq = (const float*)d_in[4];
    const float* bq = (const float*)d_in[5];
    const float* Wk = (const float*)d_in[6];
    const float* bk = (const float*)d_in[7];
    const float* Wv = (const float*)d_in[8];
    const float* bv = (const float*)d_in[9];
    const float* Wo = (const float*)d_in[10];
    const float* bo = (const float*)d_in[11];

    float* out  = (float*)d_out;                    // [2,2048,1024]
    float* attn = out + (size_t)4194304;            // [2,16,2048,2048] = 512 MB

    unsigned char* ws = (unsigned char*)d_ws;       // 48 MB used
    unsigned short* wt     = (unsigned short*)(ws);                         // 8 MB (q,k,v,o)
    unsigned short* q_hi   = (unsigned short*)(ws + (size_t)(8)  * 1048576);
    unsigned short* k_hi   = (unsigned short*)(ws + (size_t)(16) * 1048576);
    unsigned short* v_hi   = (unsigned short*)(ws + (size_t)(24) * 1048576);
    unsigned short* ctx_hi = (unsigned short*)(ws + (size_t)(32) * 1048576);
    unsigned short* vT     = (unsigned short*)(ws + (size_t)(40) * 1048576); // [b,h,d,s]

    prep_w_kernel<<<dim3(16, 16, 4), 256, 0, stream>>>(Wq, Wk, Wv, Wo, wt);
    qkv_gemm_kernel<<<768, 256, 0, stream>>>(q_in, k_in, v_in, wt, bq, bk, bv,
                                             q_hi, k_hi, v_hi);
    vtr_kernel<<<dim3(32, 32), 256, 0, stream>>>(v_hi, vT);
    attn_kernel<<<1024, 256, 0, stream>>>(q_hi, k_hi, vT, mask, attn, ctx_hi);
    out_gemm_kernel<<<256, 256, 0, stream>>>(ctx_hi, wt + (size_t)3 * 1048576, bo, out);
}